// Round 5
// baseline (269.602 us; speedup 1.0000x reference)
//
#include <hip/hip_runtime.h>
#include <hip/hip_bf16.h>
#include <math.h>

// SlotAttention on MI355X.
// Factorizations:
//   k,v never materialized:  qk = LN(slots) @ (Wq^T Wk);  logits = x·qk
//   updates feeds only the GRU input GEMM:  gi = uxr @ (wih·Wv)^T  (M precomputed)
//   token-normalization 1/(colsum+eps) commutes out of the P^T@X accumulation.
// Per iteration TWO kernels:
//   k3       : fused attention pass over x (LN-of-inputs folded into iter 0)
//   k_slotiter: reduce -> GRU(gi,gh in-reg) -> gates -> LN_m -> MLP -> LN_s -> qk
//               one block per batch, slot state never leaves the CU.

#define EPS_ 1e-8f
#define LNEPS_ 1e-5f

typedef __attribute__((ext_vector_type(8))) short bf16x8;
typedef __attribute__((ext_vector_type(4))) float f32x4;
typedef __attribute__((ext_vector_type(4))) short s16x4;

static __device__ __forceinline__ short f2bf(float f) {
  __hip_bfloat16 h = __float2bfloat16(f);
  union { __hip_bfloat16 h; short s; } u; u.h = h; return u.s;
}
static __device__ __forceinline__ float4 ld4(const float* p){ return *(const float4*)p; }

// ---------------- prep: MT = Wq^T Wk, M = wih@Wv, bf16 casts ----------------
__global__ __launch_bounds__(256) void k_prep(
    const float* __restrict__ Wq, const float* __restrict__ Wk,
    const float* __restrict__ wih, const float* __restrict__ Wv,
    const float* __restrict__ whh, const float* __restrict__ w1, const float* __restrict__ w2,
    short* __restrict__ MTb, short* __restrict__ Mb, short* __restrict__ whhb,
    short* __restrict__ w1b, short* __restrict__ w2b) {
  int blk = blockIdx.x, t = threadIdx.x;
  if (blk < 64) {                 // MT[e][f] = sum_d Wq[d][f]*Wk[d][e]
    int e0 = blk*4;
    float a0=0,a1=0,a2=0,a3=0;
    for (int d=0; d<256; d++) {
      float qv = Wq[d*256 + t];
      a0 += qv*Wk[d*256+e0];   a1 += qv*Wk[d*256+e0+1];
      a2 += qv*Wk[d*256+e0+2]; a3 += qv*Wk[d*256+e0+3];
    }
    MTb[(e0  )*256+t]=f2bf(a0); MTb[(e0+1)*256+t]=f2bf(a1);
    MTb[(e0+2)*256+t]=f2bf(a2); MTb[(e0+3)*256+t]=f2bf(a3);
  } else if (blk < 256) {         // M[n][e] = sum_d wih[n][d]*Wv[d][e]
    int n0 = (blk-64)*4;
    float a0=0,a1=0,a2=0,a3=0;
    for (int d=0; d<256; d++) {
      float vv = Wv[d*256 + t];
      a0 += wih[(n0  )*256+d]*vv; a1 += wih[(n0+1)*256+d]*vv;
      a2 += wih[(n0+2)*256+d]*vv; a3 += wih[(n0+3)*256+d]*vv;
    }
    Mb[(size_t)(n0  )*256+t]=f2bf(a0); Mb[(size_t)(n0+1)*256+t]=f2bf(a1);
    Mb[(size_t)(n0+2)*256+t]=f2bf(a2); Mb[(size_t)(n0+3)*256+t]=f2bf(a3);
  } else {                        // casts: whh 49152, w1 32768, w2 32768 float4s
    int c = (blk-256)*256 + t;
    const float* src; short* dst;
    if (c < 49152) { src=whh; dst=whhb; }
    else if ((c-=49152) < 32768) { src=w1; dst=w1b; }
    else { c-=32768; src=w2; dst=w2b; }
    float4 v = ld4(src + (size_t)c*4);
    short4 o; o.x=f2bf(v.x); o.y=f2bf(v.y); o.z=f2bf(v.z); o.w=f2bf(v.w);
    *(short4*)(dst + (size_t)c*4) = o;
  }
}

// ---------------- fused attention pass (+optional LN-of-inputs) ----------------
// grid = B*16 blocks (256 token-rows each), 256 threads = 4 waves.
template<int LNIN, int WATTN>
__global__ __launch_bounds__(256) void k3(
    const float* __restrict__ inputs, const float* __restrict__ lnw, const float* __restrict__ lnb,
    short* __restrict__ xbf, const short* __restrict__ qk, const float* __restrict__ twg,
    float* __restrict__ ux_part, float* __restrict__ colsum_part, float* __restrict__ attn_un) {
  __shared__ short Xs[64*264];
  __shared__ short QKs[16*264];
  __shared__ short Pt[16*72];
  __shared__ float tws[64];
  __shared__ float cs[16];
  __shared__ float lnwb[512];
  const int t = threadIdx.x;
  const int b = blockIdx.x >> 4;
  const int n0 = (blockIdx.x & 15) * 256;
  const int lane = t & 63, w = t >> 6, l15 = lane & 15, lg = lane >> 4;
  #pragma unroll
  for (int i=0;i<2;i++){
    int cid = t + i*256;
    int row = cid>>5, ck = cid&31;
    *(uint4*)&QKs[row*264 + ck*8] = *(const uint4*)&qk[((size_t)(b*16+row))*256 + ck*8];
  }
  if (LNIN){
    if (t < 64)       *(float4*)&lnwb[t*4]           = ld4(lnw + t*4);
    else if (t < 128) *(float4*)&lnwb[256+(t-64)*4]  = ld4(lnb + (t-64)*4);
  }
  if (t<16) cs[t]=0.f;
  f32x4 uacc[4] = {};
  for (int g=0; g<4; ++g) {
    __syncthreads();
    const size_t rowbase = (size_t)b*4096 + n0 + g*64;
    if (LNIN) {
      const float* ing = inputs + rowbase*256;
      const int r = t>>2, c = t&3;
      float4 vv[16];
      #pragma unroll
      for (int k=0;k<16;k++) vv[k] = ld4(ing + r*256 + (c+4*k)*4);
      float s=0.f, sq=0.f;
      #pragma unroll
      for (int k=0;k<16;k++){
        s  += vv[k].x+vv[k].y+vv[k].z+vv[k].w;
        sq += vv[k].x*vv[k].x+vv[k].y*vv[k].y+vv[k].z*vv[k].z+vv[k].w*vv[k].w;
      }
      s += __shfl_xor(s,1);  s += __shfl_xor(s,2);
      sq += __shfl_xor(sq,1); sq += __shfl_xor(sq,2);
      float mean = s*(1.f/256.f);
      float rstd = rsqrtf(sq*(1.f/256.f) - mean*mean + LNEPS_);
      short* xw = xbf + rowbase*256;
      #pragma unroll
      for (int k=0;k<16;k++){
        int d0 = (c+4*k)*4;
        float4 wv = *(float4*)&lnwb[d0];
        float4 bv = *(float4*)&lnwb[256+d0];
        s16x4 pk;
        pk[0]=f2bf((vv[k].x-mean)*rstd*wv.x+bv.x);
        pk[1]=f2bf((vv[k].y-mean)*rstd*wv.y+bv.y);
        pk[2]=f2bf((vv[k].z-mean)*rstd*wv.z+bv.z);
        pk[3]=f2bf((vv[k].w-mean)*rstd*wv.w+bv.w);
        *(s16x4*)&Xs[r*264 + d0] = pk;
        *(s16x4*)&xw[r*256 + d0] = pk;
      }
    } else {
      const short* xg = xbf + rowbase*256;
      #pragma unroll
      for (int r8=0;r8<8;r8++){
        int row = r8*8 + (t>>5), ck = t&31;
        *(uint4*)&Xs[row*264 + ck*8] = *(const uint4*)&xg[(size_t)row*256 + ck*8];
      }
    }
    if (t<64) tws[t] = fmaxf(twg[rowbase + t], 0.f);
    __syncthreads();
    // GEMM1: D[row][s] = x_row . qk_s
    f32x4 acc = {0.f,0.f,0.f,0.f};
    #pragma unroll
    for (int kk=0;kk<8;kk++){
      bf16x8 af  = *(const bf16x8*)&Xs[(w*16+l15)*264 + kk*32 + lg*8];
      bf16x8 bfr = *(const bf16x8*)&QKs[l15*264 + kk*32 + lg*8];
      acc = __builtin_amdgcn_mfma_f32_16x16x32_bf16(af, bfr, acc, 0,0,0);
    }
    float a4[4];
    #pragma unroll
    for (int q=0;q<4;q++){
      float v = acc[q]*0.0625f;          // * D^-0.5
      float m = v;
      #pragma unroll
      for (int d=1; d<16; d<<=1) m = fmaxf(m, __shfl_xor(m, d, 16));
      float e = __expf(v-m);
      float se = e;
      #pragma unroll
      for (int d=1; d<16; d<<=1) se += __shfl_xor(se, d, 16);
      int row = w*16 + lg*4 + q;
      float a = (e/se)*tws[row];
      a4[q] = a;
      if (WATTN)
        attn_un[(rowbase + row)*16 + l15] = a;
    }
    float psum = a4[0]+a4[1]+a4[2]+a4[3];
    psum += __shfl_xor(psum, 16);
    psum += __shfl_xor(psum, 32);
    if (lane<16) atomicAdd(&cs[l15], psum);
    s16x4 pk; pk[0]=f2bf(a4[0]); pk[1]=f2bf(a4[1]); pk[2]=f2bf(a4[2]); pk[3]=f2bf(a4[3]);
    *(s16x4*)&Pt[l15*72 + w*16 + lg*4] = pk;
    __syncthreads();
    // GEMM2: ux[s][e] += P^T @ X ; wave w owns e-cols [w*64, w*64+64)
    #pragma unroll
    for (int kk=0;kk<2;kk++){
      bf16x8 a2 = *(const bf16x8*)&Pt[l15*72 + kk*32 + lg*8];
      #pragma unroll
      for (int tt=0;tt<4;tt++){
        int col = w*64 + tt*16 + l15;
        int rbv = kk*32 + lg*8;
        bf16x8 b2;
        #pragma unroll
        for (int j=0;j<8;j++) b2[j] = Xs[(rbv+j)*264 + col];
        uacc[tt] = __builtin_amdgcn_mfma_f32_16x16x32_bf16(a2, b2, uacc[tt], 0,0,0);
      }
    }
  }
  __syncthreads();
  if (t<16) colsum_part[blockIdx.x*16 + t] = cs[t];
  #pragma unroll
  for (int tt=0;tt<4;tt++){
    #pragma unroll
    for (int q=0;q<4;q++)
      ux_part[(size_t)blockIdx.x*4096 + (lg*4+q)*256 + w*64 + tt*16 + l15] = uacc[tt][q];
  }
}

// ---------------- per-iteration slot mega-kernel ----------------
// grid 32 (one block per batch), 512 threads = 8 waves. M=16 slot rows per block.
// Output-tile ownership everywhere: rows lg*4+q, cols (wave-sliced) ct*16+l15.
// B-fragments read straight from L2-resident bf16 weights (no LDS staging).
template<int LAST>
__global__ __launch_bounds__(512) void k_slotiter(
    const float* __restrict__ uxp, const float* __restrict__ csp,
    float* __restrict__ csr, float* __restrict__ slots, float* __restrict__ outs,
    const short* __restrict__ Mb, const short* __restrict__ whhb,
    const float* __restrict__ bih, const float* __restrict__ bhh,
    const float* __restrict__ lmw, const float* __restrict__ lmb,
    const short* __restrict__ w1b, const float* __restrict__ b1,
    const short* __restrict__ w2b, const float* __restrict__ b2,
    const float* __restrict__ lsw, const float* __restrict__ lsb,
    const short* __restrict__ MTb, short* __restrict__ qk)
{
  __shared__ short uxA[16*264];   // normalized updates (bf16)
  __shared__ short slA[16*264];   // prev slots (bf16)
  __shared__ float hF [16*260];   // prev slots (f32) for gates
  __shared__ short lnA[16*264];   // LN_m output, later reused for LN_s output
  __shared__ short hbA[16*520];   // MLP hidden (bf16)
  __shared__ float csL[16];
  __shared__ float pS[8][16], pQ[8][16];
  const int t=threadIdx.x, b=blockIdx.x;
  const int w=t>>6, lane=t&63, l15=lane&15, lg=lane>>4;
  const int s=t>>5, e=(t&31)*8;
  // P0a: colsum reduce (+ raw colsum to global for attn_norm)
  if (t<16){
    float c=0.f;
    #pragma unroll
    for (int j=0;j<16;j++) c += csp[((b*16+j)<<4)+t];
    csL[t]=c+EPS_; csr[b*16+t]=c;
  }
  // P1: stage prev slots (bf16 for GEMM A, f32 for gates)
  {
    const float* sp = slots + ((size_t)(b*16+s))*256 + e;
    float4 v0=ld4(sp), v1=ld4(sp+4);
    s16x4 o0,o1;
    o0[0]=f2bf(v0.x);o0[1]=f2bf(v0.y);o0[2]=f2bf(v0.z);o0[3]=f2bf(v0.w);
    o1[0]=f2bf(v1.x);o1[1]=f2bf(v1.y);o1[2]=f2bf(v1.z);o1[3]=f2bf(v1.w);
    *(s16x4*)&slA[s*264+e]=o0; *(s16x4*)&slA[s*264+e+4]=o1;
    *(float4*)&hF[s*260+e]=v0; *(float4*)&hF[s*260+e+4]=v1;
  }
  __syncthreads();
  // P0b: reduce ux partials, fold 1/(colsum+eps), -> uxA bf16
  {
    float u0=0,u1=0,u2=0,u3=0,u4=0,u5=0,u6=0,u7=0;
    #pragma unroll
    for (int j=0;j<16;j++){
      const float* p = uxp + (((size_t)(b*16+j))<<12) + s*256 + e;
      float4 a=ld4(p), c=ld4(p+4);
      u0+=a.x;u1+=a.y;u2+=a.z;u3+=a.w;u4+=c.x;u5+=c.y;u6+=c.z;u7+=c.w;
    }
    float inv = 1.f/csL[s];
    s16x4 o0,o1;
    o0[0]=f2bf(u0*inv);o0[1]=f2bf(u1*inv);o0[2]=f2bf(u2*inv);o0[3]=f2bf(u3*inv);
    o1[0]=f2bf(u4*inv);o1[1]=f2bf(u5*inv);o1[2]=f2bf(u6*inv);o1[3]=f2bf(u7*inv);
    *(s16x4*)&uxA[s*264+e]=o0; *(s16x4*)&uxA[s*264+e+4]=o1;
  }
  __syncthreads();
  // P2: gh = slots@whh^T, gi = ux@M^T ; 6 tiles each (3 gate parts x 2), in regs.
  f32x4 gh[6], gi[6];
  #pragma unroll
  for (int p=0;p<3;p++)
    #pragma unroll
    for (int ct=0;ct<2;ct++){
      int col = p*256 + w*32 + ct*16 + l15;
      f32x4 ah={},ai={};
      #pragma unroll
      for (int kk=0;kk<8;kk++){
        bf16x8 afs=*(const bf16x8*)&slA[l15*264+kk*32+lg*8];
        bf16x8 afu=*(const bf16x8*)&uxA[l15*264+kk*32+lg*8];
        bf16x8 bw=*(const bf16x8*)&whhb[(size_t)col*256+kk*32+lg*8];
        bf16x8 bm=*(const bf16x8*)&Mb[(size_t)col*256+kk*32+lg*8];
        ah=__builtin_amdgcn_mfma_f32_16x16x32_bf16(afs,bw,ah,0,0,0);
        ai=__builtin_amdgcn_mfma_f32_16x16x32_bf16(afu,bm,ai,0,0,0);
      }
      gh[p*2+ct]=ah; gi[p*2+ct]=ai;
    }
  // P3: gates in-register (tile ownership == MLP2 ownership, residual stays in regs)
  float hn_[2][4];
  #pragma unroll
  for (int ct=0;ct<2;ct++){
    int c = w*32+ct*16+l15;
    float bir=bih[c],bhr=bhh[c],biz=bih[256+c],bhz=bhh[256+c],bin=bih[512+c],bhn=bhh[512+c];
    #pragma unroll
    for (int q=0;q<4;q++){
      float r = 1.f/(1.f+__expf(-(gi[ct][q]+bir + gh[ct][q]+bhr)));
      float z = 1.f/(1.f+__expf(-(gi[2+ct][q]+biz + gh[2+ct][q]+bhz)));
      float n = tanhf(gi[4+ct][q]+bin + r*(gh[4+ct][q]+bhn));
      float h = hF[(lg*4+q)*260 + c];
      hn_[ct][q] = (1.f-z)*n + z*h;
    }
  }
  // LN_m: per-row cross-wave reduce
  float s4[4], q4[4];
  #pragma unroll
  for (int q=0;q<4;q++){
    float a=hn_[0][q], c2=hn_[1][q];
    s4[q]=a+c2; q4[q]=a*a+c2*c2;
  }
  #pragma unroll
  for (int d=1; d<16; d<<=1)
    #pragma unroll
    for (int q=0;q<4;q++){ s4[q]+=__shfl_xor(s4[q],d,16); q4[q]+=__shfl_xor(q4[q],d,16); }
  if (l15==0)
    #pragma unroll
    for (int q=0;q<4;q++){ pS[w][lg*4+q]=s4[q]; pQ[w][lg*4+q]=q4[q]; }
  __syncthreads();
  float mean_[4], rstd_[4];
  #pragma unroll
  for (int q=0;q<4;q++){
    int row=lg*4+q; float S=0,Q=0;
    #pragma unroll
    for (int ww=0;ww<8;ww++){S+=pS[ww][row];Q+=pQ[ww][row];}
    float m=S*(1.f/256.f); mean_[q]=m; rstd_[q]=rsqrtf(Q*(1.f/256.f)-m*m+LNEPS_);
  }
  #pragma unroll
  for (int ct=0;ct<2;ct++){
    int c=w*32+ct*16+l15;
    float lw=lmw[c], lb=lmb[c];
    #pragma unroll
    for (int q=0;q<4;q++)
      lnA[(lg*4+q)*264+c] = f2bf((hn_[ct][q]-mean_[q])*rstd_[q]*lw+lb);
  }
  __syncthreads();
  // P4: MLP1 (N=512, wave owns 64 cols)
  f32x4 m1[4]={};
  #pragma unroll
  for (int kk=0;kk<8;kk++){
    bf16x8 af=*(const bf16x8*)&lnA[l15*264+kk*32+lg*8];
    #pragma unroll
    for (int ct=0;ct<4;ct++){
      int col=w*64+ct*16+l15;
      bf16x8 bw=*(const bf16x8*)&w1b[(size_t)col*256+kk*32+lg*8];
      m1[ct]=__builtin_amdgcn_mfma_f32_16x16x32_bf16(af,bw,m1[ct],0,0,0);
    }
  }
  #pragma unroll
  for (int ct=0;ct<4;ct++){
    int col=w*64+ct*16+l15;
    float bv=b1[col];
    #pragma unroll
    for (int q=0;q<4;q++){
      float v=m1[ct][q]+bv;
      v=0.5f*v*(1.f+erff(v*0.70710678118654752f));
      hbA[(lg*4+q)*520+col]=f2bf(v);
    }
  }
  __syncthreads();
  // P5: MLP2 (N=256, K=512, wave owns 32 cols) + bias + residual
  f32x4 m2[2]={};
  #pragma unroll
  for (int kk=0;kk<16;kk++){
    bf16x8 af=*(const bf16x8*)&hbA[l15*520+kk*32+lg*8];
    #pragma unroll
    for (int ct=0;ct<2;ct++){
      int col=w*32+ct*16+l15;
      bf16x8 bw=*(const bf16x8*)&w2b[(size_t)col*512+kk*32+lg*8];
      m2[ct]=__builtin_amdgcn_mfma_f32_16x16x32_bf16(af,bw,m2[ct],0,0,0);
    }
  }
  float vv[2][4];
  #pragma unroll
  for (int ct=0;ct<2;ct++){
    int col=w*32+ct*16+l15;
    float bv=b2[col];
    #pragma unroll
    for (int q=0;q<4;q++) vv[ct][q]=m2[ct][q]+bv+hn_[ct][q];
  }
  // P6: write new slots
  float* dst = LAST ? outs : slots;
  #pragma unroll
  for (int ct=0;ct<2;ct++){
    int col=w*32+ct*16+l15;
    #pragma unroll
    for (int q=0;q<4;q++)
      dst[(size_t)(b*16+lg*4+q)*256+col]=vv[ct][q];
  }
  if (LAST) return;
  // P7: LN_s + qk GEMM for next iteration
  #pragma unroll
  for (int q=0;q<4;q++){
    float a=vv[0][q], c2=vv[1][q];
    s4[q]=a+c2; q4[q]=a*a+c2*c2;
  }
  #pragma unroll
  for (int d=1; d<16; d<<=1)
    #pragma unroll
    for (int q=0;q<4;q++){ s4[q]+=__shfl_xor(s4[q],d,16); q4[q]+=__shfl_xor(q4[q],d,16); }
  if (l15==0)
    #pragma unroll
    for (int q=0;q<4;q++){ pS[w][lg*4+q]=s4[q]; pQ[w][lg*4+q]=q4[q]; }
  __syncthreads();
  #pragma unroll
  for (int q=0;q<4;q++){
    int row=lg*4+q; float S=0,Q=0;
    #pragma unroll
    for (int ww=0;ww<8;ww++){S+=pS[ww][row];Q+=pQ[ww][row];}
    float m=S*(1.f/256.f); mean_[q]=m; rstd_[q]=rsqrtf(Q*(1.f/256.f)-m*m+LNEPS_);
  }
  #pragma unroll
  for (int ct=0;ct<2;ct++){
    int c=w*32+ct*16+l15;
    float lw=lsw[c], lb=lsb[c];
    #pragma unroll
    for (int q=0;q<4;q++)
      lnA[(lg*4+q)*264+c] = f2bf((vv[ct][q]-mean_[q])*rstd_[q]*lw+lb);
  }
  __syncthreads();
  f32x4 qa[2]={};
  #pragma unroll
  for (int kk=0;kk<8;kk++){
    bf16x8 af=*(const bf16x8*)&lnA[l15*264+kk*32+lg*8];
    #pragma unroll
    for (int ct=0;ct<2;ct++){
      int col=w*32+ct*16+l15;
      bf16x8 bw=*(const bf16x8*)&MTb[(size_t)col*256+kk*32+lg*8];
      qa[ct]=__builtin_amdgcn_mfma_f32_16x16x32_bf16(af,bw,qa[ct],0,0,0);
    }
  }
  #pragma unroll
  for (int ct=0;ct<2;ct++){
    int col=w*32+ct*16+l15;
    #pragma unroll
    for (int q=0;q<4;q++)
      qk[(size_t)(b*16+lg*4+q)*256+col]=f2bf(qa[ct][q]);
  }
}

// ---------------- slot init: mu + sigma*noise, LN_s, qk_0 ----------------
// grid 8 blocks (64 slot-rows each), 256 threads. (MODE 1 of R4's k_slotend, proven.)
__global__ __launch_bounds__(256) void k_slotinit(
    const float* __restrict__ mu, const float* __restrict__ ls, const float* __restrict__ noise,
    float* __restrict__ sout, const float* __restrict__ lnsw, const float* __restrict__ lnsb,
    const short* __restrict__ MTb, short* __restrict__ qk) {
  __shared__ short Ws[256*40];
  __shared__ short lnS[64*264];
  const int t=threadIdx.x, bm=blockIdx.x;
  const int w=t>>6, lane=t&63, l15=lane&15, lg=lane>>4;
  float v[16][4];
  #pragma unroll
  for (int ct=0;ct<16;ct++){
    int col = ct*16+l15;
    float m = mu[col], sg = fmaxf(__expf(ls[col]),1e-6f);
    #pragma unroll
    for (int q=0;q<4;q++){
      int row = bm*64 + w*16 + lg*4 + q;
      v[ct][q] = m + sg*noise[(size_t)row*256+col];
    }
  }
  float s[4]={0,0,0,0}, sq[4]={0,0,0,0};
  #pragma unroll
  for (int ct=0;ct<16;ct++)
    #pragma unroll
    for (int q=0;q<4;q++){ s[q]+=v[ct][q]; sq[q]+=v[ct][q]*v[ct][q]; }
  #pragma unroll
  for (int q=0;q<4;q++){
    #pragma unroll
    for (int d=1; d<16; d<<=1){ s[q]+=__shfl_xor(s[q],d,16); sq[q]+=__shfl_xor(sq[q],d,16); }
  }
  #pragma unroll
  for (int ct=0;ct<16;ct++){
    int col = ct*16+l15;
    float lw = lnsw[col], lb = lnsb[col];
    #pragma unroll
    for (int q=0;q<4;q++){
      int row = bm*64 + w*16 + lg*4 + q;
      sout[(size_t)row*256+col] = v[ct][q];
      float mean = s[q]*(1.f/256.f);
      float rstd = rsqrtf(sq[q]*(1.f/256.f)-mean*mean+LNEPS_);
      lnS[(w*16+lg*4+q)*264 + col] = f2bf((v[ct][q]-mean)*rstd*lw+lb);
    }
  }
  f32x4 qa[16]={};
  for (int k0=0;k0<256;k0+=32){
    __syncthreads();
    #pragma unroll
    for (int i=0;i<4;i++){ int idx=t+i*256;     // 256 rows x 32 k = 1024 uint4
      *(uint4*)&Ws[(idx>>2)*40+(idx&3)*8] = *(const uint4*)&MTb[(size_t)(idx>>2)*256 + k0 + (idx&3)*8]; }
    __syncthreads();
    bf16x8 af = *(const bf16x8*)&lnS[(w*16+l15)*264 + k0 + lg*8];
    #pragma unroll
    for (int ct=0;ct<16;ct++){
      bf16x8 bfr = *(const bf16x8*)&Ws[(ct*16+l15)*40+lg*8];
      qa[ct]=__builtin_amdgcn_mfma_f32_16x16x32_bf16(af,bfr,qa[ct],0,0,0);
    }
  }
  #pragma unroll
  for (int ct=0;ct<16;ct++)
    #pragma unroll
    for (int q=0;q<4;q++)
      qk[(size_t)(bm*64+w*16+lg*4+q)*256 + ct*16+l15] = f2bf(qa[ct][q]);
}

// ---------------- final attn normalization (in place on d_out) ----------------
__global__ __launch_bounds__(256) void k_attn_norm(float* __restrict__ au,
    const float* __restrict__ cs) {
  size_t i = ((size_t)blockIdx.x*256 + threadIdx.x)*4;
  float4 v = ld4(au + i);
  int s = (int)(i & 15);
  size_t b = i >> 16;           // 4096*16 elems per batch
  const float* c = cs + b*16 + s;
  float4 o;
  o.x = v.x/(c[0]+EPS_); o.y = v.y/(c[1]+EPS_);
  o.z = v.z/(c[2]+EPS_); o.w = v.w/(c[3]+EPS_);
  *(float4*)(au + i) = o;
}

extern "C" void kernel_launch(void* const* d_in, const int* in_sizes, int n_in,
                              void* d_out, int out_size, void* d_ws, size_t ws_size,
                              hipStream_t stream) {
  const float* inputs   = (const float*)d_in[0];
  const float* token_w  = (const float*)d_in[1];
  const float* noise    = (const float*)d_in[2];
  const float* ln_in_w  = (const float*)d_in[3];
  const float* ln_in_b  = (const float*)d_in[4];
  const float* ln_s_w   = (const float*)d_in[5];
  const float* ln_s_b   = (const float*)d_in[6];
  const float* ln_m_w   = (const float*)d_in[7];
  const float* ln_m_b   = (const float*)d_in[8];
  const float* Wk       = (const float*)d_in[9];
  const float* Wv       = (const float*)d_in[10];
  const float* Wq       = (const float*)d_in[11];
  const float* gru_wih  = (const float*)d_in[12];
  const float* gru_whh  = (const float*)d_in[13];
  const float* gru_bih  = (const float*)d_in[14];
  const float* gru_bhh  = (const float*)d_in[15];
  const float* mlp_w1   = (const float*)d_in[16];
  const float* mlp_b1   = (const float*)d_in[17];
  const float* mlp_w2   = (const float*)d_in[18];
  const float* mlp_b2   = (const float*)d_in[19];
  const float* slots_mu = (const float*)d_in[20];
  const float* slots_ls = (const float*)d_in[21];

  float* out_slots = (float*)d_out;            // [32,16,256]
  float* out_attn  = out_slots + 131072;       // [32,4096,16]

  char* wsb = (char*)d_ws;
  size_t off = 0;
  short* xbf     = (short*)(wsb + off); off += 67108864;   // x bf16 [B,N,D]
  float* ux_part = (float*)(wsb + off); off += 8388608;    // [512][16][256] f32
  float* cs_part = (float*)(wsb + off); off += 32768;      // [512][16]
  float* cs_red  = (float*)(wsb + off); off += 2048;       // [B*S]
  short* qk      = (short*)(wsb + off); off += 262144;     // [B*S][D] bf16
  short* MTb     = (short*)(wsb + off); off += 131072;     // Wq^T Wk bf16
  short* Mb      = (short*)(wsb + off); off += 393216;     // wih@Wv bf16 [768][256]
  float* slots   = (float*)(wsb + off); off += 524288;     // slots f32
  short* whhb    = (short*)(wsb + off); off += 393216;
  short* w1b     = (short*)(wsb + off); off += 262144;
  short* w2b     = (short*)(wsb + off); off += 262144;

  k_prep<<<704,256,0,stream>>>(Wq, Wk, gru_wih, Wv, gru_whh, mlp_w1, mlp_w2,
                               MTb, Mb, whhb, w1b, w2b);
  k_slotinit<<<8,256,0,stream>>>(slots_mu, slots_ls, noise, slots, ln_s_w, ln_s_b, MTb, qk);
  for (int it=0; it<3; ++it) {
    if (it==0)
      k3<1,0><<<512,256,0,stream>>>(inputs, ln_in_w, ln_in_b, xbf, qk, token_w,
                                    ux_part, cs_part, out_attn);
    else if (it==1)
      k3<0,0><<<512,256,0,stream>>>(inputs, ln_in_w, ln_in_b, xbf, qk, token_w,
                                    ux_part, cs_part, out_attn);
    else
      k3<0,1><<<512,256,0,stream>>>(inputs, ln_in_w, ln_in_b, xbf, qk, token_w,
                                    ux_part, cs_part, out_attn);
    if (it<2)
      k_slotiter<0><<<32,512,0,stream>>>(ux_part, cs_part, cs_red, slots, out_slots,
                                         Mb, whhb, gru_bih, gru_bhh, ln_m_w, ln_m_b,
                                         w1b, mlp_b1, w2b, mlp_b2, ln_s_w, ln_s_b, MTb, qk);
    else
      k_slotiter<1><<<32,512,0,stream>>>(ux_part, cs_part, cs_red, slots, out_slots,
                                         Mb, whhb, gru_bih, gru_bhh, ln_m_w, ln_m_b,
                                         w1b, mlp_b1, w2b, mlp_b2, ln_s_w, ln_s_b, MTb, qk);
  }
  k_attn_norm<<<2048,256,0,stream>>>(out_attn, cs_red);
}